// Round 17
// baseline (239.205 us; speedup 1.0000x reference)
//
#include <hip/hip_runtime.h>
#include <hip/hip_bf16.h>

// 2-layer LSTM (H=32, T=512, I=1) + FC(1) + ReLU, fused, ZERO-SELECT
// 8-wave unit-split, 8 batches/block, TWO INDEPENDENT BLOCKS PER CU.
// Grid 512 x (512 threads = 8 waves) -> 2 blocks/CU = 4 waves/SIMD in two
// independent barrier domains: when block A stalls at its barrier/LDS
// drain, block B issues (attacks the measured ~50% stall; R14 showed more
// waves in the SAME barrier group fail, R12 showed fewer waves fail).
// MFMA cols = 8 batches x 2 replicas; the replica bit selects the TILE:
// lane (m, q=col>>3, s=col&7) owns the cell of tile q = unit 8V+2m+q,
// batch s -> all 64 lanes hold distinct cells (elementwise work per batch
// unchanged; MFMA per batch 2x, cheap at MfmaUtil 11%). Tile-select = 4
// cndmask. Pair-pack partner = lane^8 (one ds_swizzle + cvt_pk).
// Carried over: adjacent-unit tiles, L1 lag-2 with h0 register prefetch
// (4-parity h0 buffer), bias+x folded in MFMA C-in, parallel P/Q for L1,
// merged-rcp CELL (7 trans), one __syncthreads per step, pre-zeroed LDS.

typedef __attribute__((ext_vector_type(8))) short bf16x8;
typedef __attribute__((ext_vector_type(4))) float f32x4;
typedef __attribute__((ext_vector_type(4))) int   i32x4;

#define HID 32
#define SEQ 512
#define L2E 1.4426950408889634f
#define LSTR 20   // LDS h-row stride in dwords (16 used + 4 pad)

static __device__ __forceinline__ float fexp2(float x){ return __builtin_amdgcn_exp2f(x); }
static __device__ __forceinline__ float frcp (float x){ return __builtin_amdgcn_rcpf(x); }
static __device__ __forceinline__ short f2bf(float f){
  unsigned u = __builtin_bit_cast(unsigned, f);
  u = (u + 0x7fffu + ((u >> 16) & 1u)) >> 16;
  return (short)u;
}

// fused LSTM cell, merged-rcp form. Gates pre-scaled (i,f,o by -log2e;
// g by +2log2e):  I=e^-i, F=e^-f, O=e^-o, G=e^{2g}.
#define CELL(gi, gf, gg, go, cvr, hout) do {                         \
  const float I_ = fexp2(gi), G_ = fexp2(gg);                        \
  const float F_ = fexp2(gf), O_ = fexp2(go);                        \
  const float a_ = 1.f + I_, b_ = 1.f + G_, c_ = 1.f + F_;           \
  const float P1_ = a_ * b_;                                         \
  const float R_  = frcp(c_ * P1_);                                  \
  const float fv_ = P1_ * R_;                                        \
  const float ig_ = (G_ - 1.f) * (c_ * R_);                          \
  (cvr) = fmaf(fv_, (cvr), ig_);                                     \
  const float C2_ = fexp2((cvr) * (2.f * L2E));                      \
  (hout) = (C2_ - 1.f) * frcp((1.f + O_) * (1.f + C2_));             \
} while (0)

// pack own h with replica-partner lane (l^8): q=0 lane gets (even, odd) pair
#define HPACK(hv, pk) do {                                                    \
  const int pa_ = __builtin_amdgcn_ds_swizzle(__builtin_bit_cast(int, (hv)), 0x201F); \
  asm("v_cvt_pk_bf16_f32 %0, %1, %2" : "=v"(pk)                               \
      : "v"(hv), "v"(__builtin_bit_cast(float, pa_)));                        \
} while (0)

__global__ __launch_bounds__(512, 4) void lstm2_db2_kernel(
    const float* __restrict__ x,
    const float* __restrict__ Wih0, const float* __restrict__ Whh0,
    const float* __restrict__ bih0, const float* __restrict__ bhh0,
    const float* __restrict__ Wih1, const float* __restrict__ Whh1,
    const float* __restrict__ bih1, const float* __restrict__ bhh1,
    const float* __restrict__ Wfc, const float* __restrict__ bfc,
    float* __restrict__ out)
{
  const int tid = threadIdx.x;
  const int w   = tid >> 6;          // 0-3: L0 groups; 4-7: L1 groups
  const int l   = tid & 63;
  const int m   = l >> 4;            // k-group; D rows 4m..4m+3
  const int col = l & 15;            // MFMA N col
  const int q   = col >> 3;          // replica bit -> owned TILE
  const int s   = col & 7;           // batch slot (8 batches/block)
  const int V   = w & 3;             // unit group: units 8V..8V+7
  const bool isL1 = (w >= 4);
  const bool qb = (q != 0);

  __shared__ int   bufH0[4][8 * LSTR];   // 4 parities (lag-2 prefetch)
  __shared__ int   bufH1[2][8 * LSTR];
  __shared__ float bufFC[4][8];

  // zero-init exchange buffers (kills all t=0 special cases)
  for (int i = tid; i < 4 * 8 * LSTR; i += 512) ((int*)bufH0)[i] = 0;
  for (int i = tid; i < 2 * 8 * LSTR; i += 512) ((int*)bufH1)[i] = 0;
  __syncthreads();

  // ---- weights: tile t row rho = gate(rho&3) of unit 8V+2*(rho>>2)+t.
  //      Lane supplies A row = col. Pre-scaled: i,f,o -> -log2e; g -> +2log2e.
  const float* Wrec = isL1 ? Whh1 : Whh0;
  const float* Bi   = isL1 ? bih1 : bih0;
  const float* Bh   = isL1 ? bhh1 : bhh0;
  const int   gcol  = col & 3;             // gate type this lane's A-row feeds
  const float scA   = (gcol == 2) ? (2.0f * L2E) : (-L2E);
  bf16x8 wfR[2], wfI[2];
  f32x4  cb[2];
  float  w0x[2][4];
  #pragma unroll
  for (int t = 0; t < 2; ++t) {
    const int ga = gcol * 32 + 8 * V + 2 * (col >> 2) + t;  // A-row unit's gate row
    #pragma unroll
    for (int j = 0; j < 8; ++j) {
      wfR[t][j] = f2bf(scA * Wrec[ga * HID + (8 * m + j)]);
      wfI[t][j] = isL1 ? f2bf(scA * Wih1[ga * HID + (8 * m + j)]) : (short)0;
    }
    const int uc = 8 * V + 2 * m + t;            // cell unit of tile t (this lane)
    #pragma unroll
    for (int rr = 0; rr < 4; ++rr) {
      const float sc = (rr == 2) ? (2.0f * L2E) : (-L2E);
      cb[t][rr]  = sc * (Bi[rr * 32 + uc] + Bh[rr * 32 + uc]);
      w0x[t][rr] = isL1 ? 0.f : sc * Wih0[rr * 32 + uc];
    }
  }
  const float wfc = isL1 ? Wfc[8 * V + 2 * m + q] : 0.f;

  float cv = 0.f, hn = 0.f;
  i32x4 h0pre = {0, 0, 0, 0};        // L1: h0(i-2) register prefetch
  const float* xb = x + (size_t)(blockIdx.x * 8 + s) * SEQ;
  const int  rd = s * LSTR + 4 * m;            // b128 read: units 8m..8m+7
  const int  wb = s * LSTR + 4 * V + m;        // b32 write: own unit pair
  const bool wr = (q == 0);                    // q=0 lanes write

  float4 xcur = {0.f, 0.f, 0.f, 0.f};
  if (!isL1) xcur = *reinterpret_cast<const float4*>(xb);   // k = 0

  for (int k = 0; k < SEQ / 4; ++k) {
    float4 xnext = {0.f, 0.f, 0.f, 0.f};
    if (!isL1 && k + 1 < SEQ / 4)
      xnext = *reinterpret_cast<const float4*>(xb + (k + 1) * 4);  // prefetch
    #pragma unroll
    for (int uu = 0; uu < 4; ++uu) {
      if (!isL1) {
        // ---- L0: h0(i) from h0(i-1) in bufH0[(i-1)&3] ----
        const i32x4 hv = *(const i32x4*)&bufH0[(uu + 3) & 3][rd];
        const bf16x8 hf = __builtin_bit_cast(bf16x8, hv);
        const float xt = (uu == 0) ? xcur.x : (uu == 1) ? xcur.y
                       : (uu == 2) ? xcur.z : xcur.w;
        // bias + x folded into C-in (computes while LDS read is in flight)
        f32x4 cbx0, cbx1;
        #pragma unroll
        for (int rr = 0; rr < 4; ++rr) {
          cbx0[rr] = fmaf(w0x[0][rr], xt, cb[0][rr]);
          cbx1[rr] = fmaf(w0x[1][rr], xt, cb[1][rr]);
        }
        f32x4 A0, A1;
        A0 = __builtin_amdgcn_mfma_f32_16x16x32_bf16(wfR[0], hf, cbx0, 0, 0, 0);
        A1 = __builtin_amdgcn_mfma_f32_16x16x32_bf16(wfR[1], hf, cbx1, 0, 0, 0);
        // tile-select: lane owns tile q's cell (unit 8V+2m+q, batch s)
        const f32x4 A = qb ? A1 : A0;
        CELL(A[0], A[1], A[2], A[3], cv, hn);
        int pk;
        HPACK(hn, pk);
        if (wr) bufH0[uu][wb] = pk;    // pair (8V+2m, 8V+2m+1) = slot 4V+m
      } else {
        const bool doC = (uu >= 2) || (k > 0);   // compute h1(i-2)
        const bool doP = (uu >= 1) || (k > 0);   // prefetch h0(i-1)
        i32x4 h1v = {0, 0, 0, 0};
        if (doC) h1v = *(const i32x4*)&bufH1[(uu + 1) & 1][rd];  // h1(i-3)
        i32x4 h0next = h0pre;
        if (doP) h0next = *(const i32x4*)&bufH0[(uu + 3) & 3][rd]; // h0(i-1)
        if (doC) {
          const bf16x8 h0f = __builtin_bit_cast(bf16x8, h0pre);
          const bf16x8 h1f = __builtin_bit_cast(bf16x8, h1v);
          const f32x4 z4 = {0.f, 0.f, 0.f, 0.f};
          f32x4 P0, P1, Q0, Q1;
          __builtin_amdgcn_s_setprio(1);
          P0 = __builtin_amdgcn_mfma_f32_16x16x32_bf16(wfI[0], h0f, cb[0], 0, 0, 0);
          P1 = __builtin_amdgcn_mfma_f32_16x16x32_bf16(wfI[1], h0f, cb[1], 0, 0, 0);
          Q0 = __builtin_amdgcn_mfma_f32_16x16x32_bf16(wfR[0], h1f, z4, 0, 0, 0);
          Q1 = __builtin_amdgcn_mfma_f32_16x16x32_bf16(wfR[1], h1f, z4, 0, 0, 0);
          __builtin_amdgcn_s_setprio(0);
          const f32x4 A0 = P0 + Q0;
          const f32x4 A1 = P1 + Q1;
          const f32x4 A = qb ? A1 : A0;
          CELL(A[0], A[1], A[2], A[3], cv, hn);
          int pk;
          HPACK(hn, pk);
          if (wr) bufH1[uu & 1][wb] = pk;  // h1(i-2) -> slot (i-2)&1 = i&1
        }
        h0pre = h0next;
      }
      __syncthreads();
    }
    xcur = xnext;
  }

  // ---- epilogue: L1 still owes h1(510), h1(511) ----
  if (isL1) {
    // h1(510) = f(h0(510)=h0pre, h1(509)=bufH1[1])
    const i32x4 h1v = *(const i32x4*)&bufH1[1][rd];
    const bf16x8 h0f = __builtin_bit_cast(bf16x8, h0pre);
    const bf16x8 h1f = __builtin_bit_cast(bf16x8, h1v);
    f32x4 A0, A1;
    A0 = __builtin_amdgcn_mfma_f32_16x16x32_bf16(wfI[0], h0f, cb[0], 0, 0, 0);
    A1 = __builtin_amdgcn_mfma_f32_16x16x32_bf16(wfI[1], h0f, cb[1], 0, 0, 0);
    A0 = __builtin_amdgcn_mfma_f32_16x16x32_bf16(wfR[0], h1f, A0, 0, 0, 0);
    A1 = __builtin_amdgcn_mfma_f32_16x16x32_bf16(wfR[1], h1f, A1, 0, 0, 0);
    const f32x4 A = qb ? A1 : A0;
    CELL(A[0], A[1], A[2], A[3], cv, hn);
    int pk;
    HPACK(hn, pk);
    if (wr) bufH1[0][wb] = pk;         // h1(510)
  }
  __syncthreads();
  if (isL1) {
    // h1(511) = f(h0(511)=bufH0[3], h1(510)=bufH1[0]); then FC partial
    const i32x4 h0v = *(const i32x4*)&bufH0[3][rd];
    const i32x4 h1v = *(const i32x4*)&bufH1[0][rd];
    const bf16x8 h0f = __builtin_bit_cast(bf16x8, h0v);
    const bf16x8 h1f = __builtin_bit_cast(bf16x8, h1v);
    f32x4 A0, A1;
    A0 = __builtin_amdgcn_mfma_f32_16x16x32_bf16(wfI[0], h0f, cb[0], 0, 0, 0);
    A1 = __builtin_amdgcn_mfma_f32_16x16x32_bf16(wfI[1], h0f, cb[1], 0, 0, 0);
    A0 = __builtin_amdgcn_mfma_f32_16x16x32_bf16(wfR[0], h1f, A0, 0, 0, 0);
    A1 = __builtin_amdgcn_mfma_f32_16x16x32_bf16(wfR[1], h1f, A1, 0, 0, 0);
    const f32x4 A = qb ? A1 : A0;
    CELL(A[0], A[1], A[2], A[3], cv, hn);
    float part = hn * wfc;
    part += __shfl_xor(part, 8);    // sum over q (tile replicas)
    part += __shfl_xor(part, 16);   // sum over m
    part += __shfl_xor(part, 32);
    if (l < 8) bufFC[V][l] = part;  // l<8 -> m=0,q=0, s=l
  }
  __syncthreads();
  if (w == 4 && l < 8) {
    const float o = bufFC[0][l] + bufFC[1][l] + bufFC[2][l] + bufFC[3][l] + bfc[0];
    out[blockIdx.x * 8 + l] = o > 0.f ? o : 0.f;
  }
}

extern "C" void kernel_launch(void* const* d_in, const int* in_sizes, int n_in,
                              void* d_out, int out_size, void* d_ws, size_t ws_size,
                              hipStream_t stream) {
  const float* x    = (const float*)d_in[0];
  const float* Wih0 = (const float*)d_in[1];
  const float* Whh0 = (const float*)d_in[2];
  const float* bih0 = (const float*)d_in[3];
  const float* bhh0 = (const float*)d_in[4];
  const float* Wih1 = (const float*)d_in[5];
  const float* Whh1 = (const float*)d_in[6];
  const float* bih1 = (const float*)d_in[7];
  const float* bhh1 = (const float*)d_in[8];
  const float* Wfc  = (const float*)d_in[9];
  const float* bfc  = (const float*)d_in[10];

  const int B = 4096;
  const int grid = B / 8;   // 512 blocks x 8 waves -> 2 blocks/CU, 4 waves/SIMD
  lstm2_db2_kernel<<<grid, 512, 0, stream>>>(
      x, Wih0, Whh0, bih0, bhh0, Wih1, Whh1, bih1, bhh1, Wfc, bfc,
      (float*)d_out);
}